// Round 18
// baseline (72.493 us; speedup 1.0000x reference)
//
#include <hip/hip_runtime.h>
#include <cstdint>
#include <cstddef>

#define BATCH 32
#define IMH 512
#define IMW 512
#define KMAX 256

// K1: register rolling-window NMS. ONE wave per block: 256 cols (4/lane), 8 rows.
#define RPW 8
#define NBLKX 2
#define NLIST (NBLKX * (IMH / RPW))    // 128 lists/image
#define NMID 32                        // lists/image after merge4
#define WCAP 512                       // worst-case strict maxima in 256x8

#define TPB2 512                       // tail threads (8 waves)

typedef unsigned long long u64;

__device__ __forceinline__ float sigmoidf_(float x) {
    return 1.0f / (1.0f + expf(-x));
}
__device__ __forceinline__ float scoref_(float r, float u) {
    const float sg = sigmoidf_(r);
    return sg * sg * (1.0f - 0.35f * sigmoidf_(u));
}

// ---------------------------------------------------------------------------
// Register-resident wave-level bitonic sort (named scalars; verified R17).
// Element e = r*64 + lane over regs v0..v3 (N=256), descending.
// ---------------------------------------------------------------------------
#define SHF(v, jj, dm) do {                                         \
    const u64 o_ = __shfl_xor((v), (jj), 64);                       \
    const bool km_ = (((lane & (jj)) == 0) == (dm));                \
    const u64 mn_ = ((v) < o_) ? (v) : o_;                          \
    const u64 mx_ = ((v) < o_) ? o_ : (v);                          \
    (v) = km_ ? mx_ : mn_;                                          \
} while (0)

#define RMAX(a, b) do {                                             \
    const u64 hi_ = ((a) > (b)) ? (a) : (b);                        \
    const u64 lo_ = ((a) > (b)) ? (b) : (a);                        \
    (a) = hi_; (b) = lo_;                                           \
} while (0)

#define RMIN(a, b) do {                                             \
    const u64 hi_ = ((a) > (b)) ? (a) : (b);                        \
    const u64 lo_ = ((a) > (b)) ? (b) : (a);                        \
    (a) = lo_; (b) = hi_;                                           \
} while (0)

__device__ __forceinline__ void clean256(u64& v0, u64& v1, u64& v2, u64& v3,
                                         const int lane) {
    RMAX(v0, v2); RMAX(v1, v3);
    RMAX(v0, v1); RMAX(v2, v3);
    #pragma unroll
    for (int j = 32; j > 0; j >>= 1) {
        SHF(v0, j, true); SHF(v1, j, true); SHF(v2, j, true); SHF(v3, j, true);
    }
}

__device__ __forceinline__ void sort256(u64& v0, u64& v1, u64& v2, u64& v3,
                                        const int lane) {
    #pragma unroll
    for (int k = 2; k <= 32; k <<= 1) {
        #pragma unroll
        for (int j = k >> 1; j > 0; j >>= 1) {
            const bool dm = ((lane & k) == 0);
            SHF(v0, j, dm); SHF(v1, j, dm); SHF(v2, j, dm); SHF(v3, j, dm);
        }
    }
    #pragma unroll
    for (int j = 32; j > 0; j >>= 1) {
        SHF(v0, j, true); SHF(v1, j, false); SHF(v2, j, true); SHF(v3, j, false);
    }
    RMAX(v0, v1); RMIN(v2, v3);
    #pragma unroll
    for (int j = 32; j > 0; j >>= 1) {
        SHF(v0, j, true); SHF(v1, j, true); SHF(v2, j, false); SHF(v3, j, false);
    }
    clean256(v0, v1, v2, v3, lane);
}

__device__ __forceinline__ void merge256(u64& v0, u64& v1, u64& v2, u64& v3,
                                         u64 w0, u64 w1, u64 w2, u64 w3,
                                         const int lane) {
    const int rl = 63 ^ lane;
    const u64 b0 = __shfl(w3, rl, 64);
    const u64 b1 = __shfl(w2, rl, 64);
    const u64 b2 = __shfl(w1, rl, 64);
    const u64 b3 = __shfl(w0, rl, 64);
    v0 = (v0 > b0) ? v0 : b0;
    v1 = (v1 > b1) ? v1 : b1;
    v2 = (v2 > b2) ? v2 : b2;
    v3 = (v3 > b3) ? v3 : b3;
    clean256(v0, v1, v2, v3, lane);
}

// ---------------------------------------------------------------------------
// K1: ONE WAVE per block, ZERO barriers. Stream score+NMS over a 256x8 strip,
// append candidates to the wave's own LDS region (same-wave RAW: no barrier),
// register-sort (256 fast path / 512 via two sorts + merge), write the sorted
// top-256 straight from registers to a fixed global segment. Tournament
// property: any global top-256 key is in its strip's top-256.
// key = (score_bits<<32) | ~idx -> unsigned desc == (score desc, idx asc),
// matching lax.top_k's stable tie-break.
// ---------------------------------------------------------------------------
__global__ __launch_bounds__(64)
void score_nms_kernel(const float* __restrict__ route,
                      const float* __restrict__ unc,
                      u64* __restrict__ top) {
    const int b    = blockIdx.z;
    const int lane = threadIdx.x;
    const int y0   = blockIdx.y * RPW;
    const int x0   = blockIdx.x * 256 + lane * 4;
    const int blk  = blockIdx.y * NBLKX + blockIdx.x;

    __shared__ u64 myR[WCAP];            // 4 KB, this wave's region

    const float* rB = route + (size_t)b * IMH * IMW;
    const float* uB = unc   + (size_t)b * IMH * IMW;

    int ex = -1;
    if (lane == 0)       ex = x0 - 1;
    else if (lane == 63) ex = x0 + 4;
    const bool eAct = (ex >= 0 && ex < IMW);

    const u64 laneMaskLt = (1ull << lane) - 1ull;
    int wcnt = 0;

    float sP[4], hP1[4], hP2[4];
    #pragma unroll
    for (int j = 0; j < 4; ++j) { sP[j] = -INFINITY; hP1[j] = -INFINITY; hP2[j] = -INFINITY; }

    const int ylast = y0 + RPW;
    bool v = (y0 - 1 >= 0);
    float4 r4, u4; float er = 0.f, eu = 0.f;
    if (v) {
        r4 = *(const float4*)(rB + (size_t)(y0 - 1) * IMW + x0);
        u4 = *(const float4*)(uB + (size_t)(y0 - 1) * IMW + x0);
        if (eAct) { er = rB[(size_t)(y0 - 1) * IMW + ex]; eu = uB[(size_t)(y0 - 1) * IMW + ex]; }
    }

    for (int y = y0 - 1; y <= ylast; ++y) {
        const int yn = y + 1;
        const bool vn = (yn <= ylast) && (yn < IMH);
        float4 r4n, u4n; float ern = 0.f, eun = 0.f;
        if (vn) {
            r4n = *(const float4*)(rB + (size_t)yn * IMW + x0);
            u4n = *(const float4*)(uB + (size_t)yn * IMW + x0);
            if (eAct) { ern = rB[(size_t)yn * IMW + ex]; eun = uB[(size_t)yn * IMW + ex]; }
        }

        float sC[4], hmC[4];
        float es = -INFINITY;
        if (v && eAct) es = scoref_(er, eu);
        if (v) {
            sC[0] = scoref_(r4.x, u4.x);
            sC[1] = scoref_(r4.y, u4.y);
            sC[2] = scoref_(r4.z, u4.z);
            sC[3] = scoref_(r4.w, u4.w);
        } else {
            sC[0] = sC[1] = sC[2] = sC[3] = -INFINITY;
        }
        float lft = __shfl_up(sC[3], 1, 64);
        if (lane == 0) lft = es;
        float rgt = __shfl_down(sC[0], 1, 64);
        if (lane == 63) rgt = es;
        if (v) {
            hmC[0] = fmaxf(fmaxf(lft,   sC[0]), sC[1]);
            hmC[1] = fmaxf(fmaxf(sC[0], sC[1]), sC[2]);
            hmC[2] = fmaxf(fmaxf(sC[1], sC[2]), sC[3]);
            hmC[3] = fmaxf(fmaxf(sC[2], sC[3]), rgt);
        } else {
            hmC[0] = hmC[1] = hmC[2] = hmC[3] = -INFINITY;
        }

        if (y >= y0 + 1) {
            const int yo = y - 1;
            bool p[4]; int cntT = 0;
            #pragma unroll
            for (int j = 0; j < 4; ++j) {
                const float m9 = fmaxf(fmaxf(hP2[j], hP1[j]), hmC[j]);
                p[j] = (sP[j] >= m9);
                cntT += p[j] ? 1 : 0;
            }
            const u64 B0 = __ballot(cntT & 1);
            const u64 B1 = __ballot(cntT & 2);
            const u64 B2 = __ballot(cntT & 4);
            const int total = __popcll(B0) + 2 * __popcll(B1) + 4 * __popcll(B2);
            if (total > 0) {
                const int prefix = __popcll(B0 & laneMaskLt) + 2 * __popcll(B1 & laneMaskLt)
                                 + 4 * __popcll(B2 & laneMaskLt);
                int mb = wcnt + prefix;
                #pragma unroll
                for (int j = 0; j < 4; ++j) {
                    if (p[j]) {
                        const unsigned idx = (unsigned)(yo * IMW + (x0 + j));
                        const u64 key = ((u64)__float_as_uint(sP[j]) << 32) | (unsigned)(~idx);
                        if (mb < WCAP) myR[mb] = key;
                        ++mb;
                    }
                }
                wcnt += total;
            }
        }

        #pragma unroll
        for (int j = 0; j < 4; ++j) { hP2[j] = hP1[j]; hP1[j] = hmC[j]; sP[j] = sC[j]; }
        r4 = r4n; u4 = u4n; er = ern; eu = eun; v = vn;
    }

    // ---- register sort of this wave's candidates (no barrier needed) ----
    const int m = (wcnt < WCAP) ? wcnt : WCAP;
    u64 v0, v1, v2, v3;
    v0 = (lane       < m) ? myR[lane]       : 0ull;
    v1 = (lane + 64  < m) ? myR[lane + 64]  : 0ull;
    v2 = (lane + 128 < m) ? myR[lane + 128] : 0ull;
    v3 = (lane + 192 < m) ? myR[lane + 192] : 0ull;
    sort256(v0, v1, v2, v3, lane);
    if (m > 256) {
        u64 w0, w1, w2, w3;
        w0 = (lane + 256 < m) ? myR[lane + 256] : 0ull;
        w1 = (lane + 320 < m) ? myR[lane + 320] : 0ull;
        w2 = (lane + 384 < m) ? myR[lane + 384] : 0ull;
        w3 = (lane + 448 < m) ? myR[lane + 448] : 0ull;
        sort256(w0, w1, w2, w3, lane);
        merge256(v0, v1, v2, v3, w0, w1, w2, w3, lane);
    }

    // flush sorted top-256 straight from registers
    u64* seg = top + ((size_t)b * NLIST + blk) * KMAX;
    seg[lane]       = v0;
    seg[lane + 64]  = v1;
    seg[lane + 128] = v2;
    seg[lane + 192] = v3;
}

// ---------------------------------------------------------------------------
// K2a: ONE WAVE per block. Register-merge 4 sorted lists -> 1 (two merge256 +
// final merge256). 128 lists/image -> 32.
// ---------------------------------------------------------------------------
__global__ __launch_bounds__(64)
void merge4_kernel(const u64* __restrict__ top,
                   u64* __restrict__ mid) {
    const int o    = blockIdx.x;         // 0..31
    const int b    = blockIdx.y;
    const int lane = threadIdx.x;

    const u64* L = top + ((size_t)b * NLIST + o * 4) * KMAX;

    u64 a0 = L[lane],            a1 = L[lane + 64],
        a2 = L[lane + 128],      a3 = L[lane + 192];
    {
        const u64 w0 = L[KMAX + lane],       w1 = L[KMAX + lane + 64],
                  w2 = L[KMAX + lane + 128], w3 = L[KMAX + lane + 192];
        merge256(a0, a1, a2, a3, w0, w1, w2, w3, lane);
    }
    u64 c0 = L[2 * KMAX + lane],        c1 = L[2 * KMAX + lane + 64],
        c2 = L[2 * KMAX + lane + 128],  c3 = L[2 * KMAX + lane + 192];
    {
        const u64 w0 = L[3 * KMAX + lane],       w1 = L[3 * KMAX + lane + 64],
                  w2 = L[3 * KMAX + lane + 128], w3 = L[3 * KMAX + lane + 192];
        merge256(c0, c1, c2, c3, w0, w1, w2, w3, lane);
    }
    merge256(a0, a1, a2, a3, c0, c1, c2, c3, lane);

    u64* out = mid + ((size_t)b * NMID + o) * KMAX;
    out[lane]       = a0;
    out[lane + 64]  = a1;
    out[lane + 128] = a2;
    out[lane + 192] = a3;
}

// ---------------------------------------------------------------------------
// K3 (tail): 1 block/image x 512 threads. 32 sorted-desc 256-lists ->
// 5 rounds of pairwise top-256 merge (D[i] = max(A[i], B[255-i]) + 8-phase
// bitonic clean). Final list = exact sorted global top-256 -> ROI epilogue.
// ---------------------------------------------------------------------------
__global__ __launch_bounds__(TPB2)
void tail_kernel(const u64* __restrict__ mid,
                 const float* __restrict__ scale,
                 const float* __restrict__ unc,
                 const int* __restrict__ imh,
                 const int* __restrict__ imw,
                 float* __restrict__ rois,
                 float* __restrict__ scoresOut,
                 float* __restrict__ validOut) {
    const int b   = blockIdx.x;
    const int tid = threadIdx.x;

    __shared__ u64 bufA[NMID * KMAX];        // 64 KB
    __shared__ u64 bufB[(NMID / 2) * KMAX];  // 32 KB

    const u64* tb = mid + (size_t)b * NMID * KMAX;
    for (int i = tid; i < NMID * KMAX; i += TPB2) bufA[i] = tb[i];
    __syncthreads();

    u64* src = bufA;
    u64* dst = bufB;
    int nl = NMID;
    while (nl > 1) {
        const int half = nl >> 1;
        const int E = half * KMAX;
        for (int p = tid; p < E; p += TPB2) {
            const int h = p >> 8;
            const int i = p & (KMAX - 1);
            const u64 a = src[(2 * h) * KMAX + i];
            const u64 c = src[(2 * h + 1) * KMAX + (KMAX - 1 - i)];
            dst[p] = (a > c) ? a : c;
        }
        __syncthreads();
        for (int j = KMAX >> 1; j > 0; j >>= 1) {
            for (int p = tid; p < (E >> 1); p += TPB2) {
                const int i   = ((p & ~(j - 1)) << 1) | (p & (j - 1));
                const int ixj = i | j;
                const u64 a = dst[i];
                const u64 c = dst[ixj];
                if (a < c) { dst[i] = c; dst[ixj] = a; }
            }
            __syncthreads();
        }
        u64* t = src; src = dst; dst = t;
        nl = half;
    }

    if (tid < KMAX) {
        const u64 k = src[tid];
        const float value = __uint_as_float((unsigned)(k >> 32));
        const bool valid  = (k != 0ull) && (value > 0.0f);

        float r0 = 0.f, r1 = 0.f, r2 = 0.f, r3 = 0.f, r4 = 0.f, sv = 0.f, vv = 0.f;
        if (valid) {
            const unsigned idx = ~(unsigned)(k & 0xFFFFFFFFull);
            const int y = (int)(idx / IMW);
            const int x = (int)(idx % IMW);
            const float cx = ((float)x + 0.5f) * 4.0f;
            const float cy = ((float)y + 0.5f) * 4.0f;
            const float sg = scale[(size_t)b * IMH * IMW + idx];
            const float uu = unc[(size_t)b * IMH * IMW + idx];
            const float su = sigmoidf_(uu);
            float side = 32.0f + sigmoidf_(sg) * (512.0f - 32.0f);
            side = side * (1.0f + 0.25f * su);
            const float half2 = side * 0.5f;
            const float fw = (float)imw[0];
            const float fh = (float)imh[0];
            r0 = (float)b;
            r1 = fminf(fmaxf(cx - half2, 0.0f), fw - 1.0f);
            r2 = fminf(fmaxf(cy - half2, 0.0f), fh - 1.0f);
            r3 = fminf(fmaxf(cx + half2, 1.0f), fw);
            r4 = fminf(fmaxf(cy + half2, 1.0f), fh);
            sv = value;
            vv = 1.0f;
        }
        float* roiP = rois + ((size_t)b * KMAX + tid) * 5;
        roiP[0] = r0; roiP[1] = r1; roiP[2] = r2; roiP[3] = r3; roiP[4] = r4;
        scoresOut[b * KMAX + tid] = sv;
        validOut[b * KMAX + tid]  = vv;
    }
}

extern "C" void kernel_launch(void* const* d_in, const int* in_sizes, int n_in,
                              void* d_out, int out_size, void* d_ws, size_t ws_size,
                              hipStream_t stream) {
    const float* route = (const float*)d_in[0];
    const float* scale = (const float*)d_in[1];
    const float* unc   = (const float*)d_in[2];
    const int*   imh   = (const int*)d_in[3];
    const int*   imw   = (const int*)d_in[4];

    // ws layout: [top B*128*256 u64 = 8MB][mid B*32*256 u64 = 2MB]
    u64* top = (u64*)d_ws;
    u64* mid = top + (size_t)BATCH * NLIST * KMAX;

    float* rois      = (float*)d_out;                       // [B, 256, 5]
    float* scoresOut = rois + (size_t)BATCH * KMAX * 5;     // [B, 256]
    float* validOut  = scoresOut + (size_t)BATCH * KMAX;    // [B, 256]

    dim3 grid1(NBLKX, IMH / RPW, BATCH);   // 2 x 64 x 32 = 4096 wave-blocks
    score_nms_kernel<<<grid1, 64, 0, stream>>>(route, unc, top);

    dim3 grid2(NMID, BATCH);               // 32 x 32 wave-blocks
    merge4_kernel<<<grid2, 64, 0, stream>>>(top, mid);

    tail_kernel<<<BATCH, TPB2, 0, stream>>>(mid, scale, unc,
                                            imh, imw, rois, scoresOut, validOut);
}

// Round 19
// 64.610 us; speedup vs baseline: 1.1220x; 1.1220x over previous
//
#include <hip/hip_runtime.h>
#include <cstdint>
#include <cstddef>

#define BATCH 32
#define IMH 512
#define IMW 512
#define KMAX 256

// K1: register rolling-window NMS. ONE wave per block: 256 cols (4/lane), 8 rows.
#define RPW 8
#define NBLKX 2
#define NLIST (NBLKX * (IMH / RPW))    // 128 lists/image
#define NMID 32                        // lists/image after merge4
#define WCAP 512                       // worst-case strict maxima in 256x8

#define TPB2 512                       // tail threads (8 waves)

typedef unsigned long long u64;

__device__ __forceinline__ float sigmoidf_(float x) {
    return 1.0f / (1.0f + expf(-x));
}
__device__ __forceinline__ float scoref_(float r, float u) {
    const float sg = sigmoidf_(r);
    return sg * sg * (1.0f - 0.35f * sigmoidf_(u));
}

// ---------------------------------------------------------------------------
// Register-resident wave-level bitonic sort (named scalars; network identical
// to the R17/R18-verified version). FOLDED compare-exchange: take the partner
// value iff (mine < partner) == want_max — 1 u64 cmp + 2 cndmask instead of
// computing min and max separately (6 cndmask). Equal keys only occur for
// zero-padding, where either choice yields the same value.
// ---------------------------------------------------------------------------
#define SHF(v, jj, dm) do {                                         \
    const u64 o_ = __shfl_xor((v), (jj), 64);                       \
    const bool take_ = ((((lane & (jj)) == 0) == (dm)) == ((v) < o_)); \
    (v) = take_ ? o_ : (v);                                         \
} while (0)

#define RMAX(a, b) do {                                             \
    const u64 hi_ = ((a) > (b)) ? (a) : (b);                        \
    const u64 lo_ = ((a) > (b)) ? (b) : (a);                        \
    (a) = hi_; (b) = lo_;                                           \
} while (0)

#define RMIN(a, b) do {                                             \
    const u64 hi_ = ((a) > (b)) ? (a) : (b);                        \
    const u64 lo_ = ((a) > (b)) ? (b) : (a);                        \
    (a) = lo_; (b) = hi_;                                           \
} while (0)

__device__ __forceinline__ void clean256(u64& v0, u64& v1, u64& v2, u64& v3,
                                         const int lane) {
    RMAX(v0, v2); RMAX(v1, v3);
    RMAX(v0, v1); RMAX(v2, v3);
    #pragma unroll
    for (int j = 32; j > 0; j >>= 1) {
        SHF(v0, j, true); SHF(v1, j, true); SHF(v2, j, true); SHF(v3, j, true);
    }
}

__device__ __forceinline__ void sort256(u64& v0, u64& v1, u64& v2, u64& v3,
                                        const int lane) {
    #pragma unroll
    for (int k = 2; k <= 32; k <<= 1) {
        #pragma unroll
        for (int j = k >> 1; j > 0; j >>= 1) {
            const bool dm = ((lane & k) == 0);
            SHF(v0, j, dm); SHF(v1, j, dm); SHF(v2, j, dm); SHF(v3, j, dm);
        }
    }
    #pragma unroll
    for (int j = 32; j > 0; j >>= 1) {
        SHF(v0, j, true); SHF(v1, j, false); SHF(v2, j, true); SHF(v3, j, false);
    }
    RMAX(v0, v1); RMIN(v2, v3);
    #pragma unroll
    for (int j = 32; j > 0; j >>= 1) {
        SHF(v0, j, true); SHF(v1, j, true); SHF(v2, j, false); SHF(v3, j, false);
    }
    clean256(v0, v1, v2, v3, lane);
}

__device__ __forceinline__ void merge256(u64& v0, u64& v1, u64& v2, u64& v3,
                                         u64 w0, u64 w1, u64 w2, u64 w3,
                                         const int lane) {
    const int rl = 63 ^ lane;
    const u64 b0 = __shfl(w3, rl, 64);
    const u64 b1 = __shfl(w2, rl, 64);
    const u64 b2 = __shfl(w1, rl, 64);
    const u64 b3 = __shfl(w0, rl, 64);
    v0 = (v0 > b0) ? v0 : b0;
    v1 = (v1 > b1) ? v1 : b1;
    v2 = (v2 > b2) ? v2 : b2;
    v3 = (v3 > b3) ? v3 : b3;
    clean256(v0, v1, v2, v3, lane);
}

// ---------------------------------------------------------------------------
// K1: ONE WAVE per block, ZERO barriers. Stream score+NMS over a 256x8 strip,
// append candidates to the wave's own LDS region (same-wave RAW: no barrier),
// register-sort (256 fast path / 512 via two sorts + merge), write the sorted
// top-256 straight from registers to a fixed global segment. Tournament
// property: any global top-256 key is in its strip's top-256.
// key = (score_bits<<32) | ~idx -> unsigned desc == (score desc, idx asc),
// matching lax.top_k's stable tie-break.
// ---------------------------------------------------------------------------
__global__ __launch_bounds__(64)
void score_nms_kernel(const float* __restrict__ route,
                      const float* __restrict__ unc,
                      u64* __restrict__ top) {
    const int b    = blockIdx.z;
    const int lane = threadIdx.x;
    const int y0   = blockIdx.y * RPW;
    const int x0   = blockIdx.x * 256 + lane * 4;
    const int blk  = blockIdx.y * NBLKX + blockIdx.x;

    __shared__ u64 myR[WCAP];            // 4 KB, this wave's region

    const float* rB = route + (size_t)b * IMH * IMW;
    const float* uB = unc   + (size_t)b * IMH * IMW;

    int ex = -1;
    if (lane == 0)       ex = x0 - 1;
    else if (lane == 63) ex = x0 + 4;
    const bool eAct = (ex >= 0 && ex < IMW);

    const u64 laneMaskLt = (1ull << lane) - 1ull;
    int wcnt = 0;

    float sP[4], hP1[4], hP2[4];
    #pragma unroll
    for (int j = 0; j < 4; ++j) { sP[j] = -INFINITY; hP1[j] = -INFINITY; hP2[j] = -INFINITY; }

    const int ylast = y0 + RPW;
    bool v = (y0 - 1 >= 0);
    float4 r4, u4; float er = 0.f, eu = 0.f;
    if (v) {
        r4 = *(const float4*)(rB + (size_t)(y0 - 1) * IMW + x0);
        u4 = *(const float4*)(uB + (size_t)(y0 - 1) * IMW + x0);
        if (eAct) { er = rB[(size_t)(y0 - 1) * IMW + ex]; eu = uB[(size_t)(y0 - 1) * IMW + ex]; }
    }

    for (int y = y0 - 1; y <= ylast; ++y) {
        const int yn = y + 1;
        const bool vn = (yn <= ylast) && (yn < IMH);
        float4 r4n, u4n; float ern = 0.f, eun = 0.f;
        if (vn) {
            r4n = *(const float4*)(rB + (size_t)yn * IMW + x0);
            u4n = *(const float4*)(uB + (size_t)yn * IMW + x0);
            if (eAct) { ern = rB[(size_t)yn * IMW + ex]; eun = uB[(size_t)yn * IMW + ex]; }
        }

        float sC[4], hmC[4];
        float es = -INFINITY;
        if (v && eAct) es = scoref_(er, eu);
        if (v) {
            sC[0] = scoref_(r4.x, u4.x);
            sC[1] = scoref_(r4.y, u4.y);
            sC[2] = scoref_(r4.z, u4.z);
            sC[3] = scoref_(r4.w, u4.w);
        } else {
            sC[0] = sC[1] = sC[2] = sC[3] = -INFINITY;
        }
        float lft = __shfl_up(sC[3], 1, 64);
        if (lane == 0) lft = es;
        float rgt = __shfl_down(sC[0], 1, 64);
        if (lane == 63) rgt = es;
        if (v) {
            hmC[0] = fmaxf(fmaxf(lft,   sC[0]), sC[1]);
            hmC[1] = fmaxf(fmaxf(sC[0], sC[1]), sC[2]);
            hmC[2] = fmaxf(fmaxf(sC[1], sC[2]), sC[3]);
            hmC[3] = fmaxf(fmaxf(sC[2], sC[3]), rgt);
        } else {
            hmC[0] = hmC[1] = hmC[2] = hmC[3] = -INFINITY;
        }

        if (y >= y0 + 1) {
            const int yo = y - 1;
            bool p[4]; int cntT = 0;
            #pragma unroll
            for (int j = 0; j < 4; ++j) {
                const float m9 = fmaxf(fmaxf(hP2[j], hP1[j]), hmC[j]);
                p[j] = (sP[j] >= m9);
                cntT += p[j] ? 1 : 0;
            }
            const u64 B0 = __ballot(cntT & 1);
            const u64 B1 = __ballot(cntT & 2);
            const u64 B2 = __ballot(cntT & 4);
            const int total = __popcll(B0) + 2 * __popcll(B1) + 4 * __popcll(B2);
            if (total > 0) {
                const int prefix = __popcll(B0 & laneMaskLt) + 2 * __popcll(B1 & laneMaskLt)
                                 + 4 * __popcll(B2 & laneMaskLt);
                int mb = wcnt + prefix;
                #pragma unroll
                for (int j = 0; j < 4; ++j) {
                    if (p[j]) {
                        const unsigned idx = (unsigned)(yo * IMW + (x0 + j));
                        const u64 key = ((u64)__float_as_uint(sP[j]) << 32) | (unsigned)(~idx);
                        if (mb < WCAP) myR[mb] = key;
                        ++mb;
                    }
                }
                wcnt += total;
            }
        }

        #pragma unroll
        for (int j = 0; j < 4; ++j) { hP2[j] = hP1[j]; hP1[j] = hmC[j]; sP[j] = sC[j]; }
        r4 = r4n; u4 = u4n; er = ern; eu = eun; v = vn;
    }

    // ---- register sort of this wave's candidates (no barrier needed) ----
    const int m = (wcnt < WCAP) ? wcnt : WCAP;
    u64 v0, v1, v2, v3;
    v0 = (lane       < m) ? myR[lane]       : 0ull;
    v1 = (lane + 64  < m) ? myR[lane + 64]  : 0ull;
    v2 = (lane + 128 < m) ? myR[lane + 128] : 0ull;
    v3 = (lane + 192 < m) ? myR[lane + 192] : 0ull;
    sort256(v0, v1, v2, v3, lane);
    if (m > 256) {
        u64 w0, w1, w2, w3;
        w0 = (lane + 256 < m) ? myR[lane + 256] : 0ull;
        w1 = (lane + 320 < m) ? myR[lane + 320] : 0ull;
        w2 = (lane + 384 < m) ? myR[lane + 384] : 0ull;
        w3 = (lane + 448 < m) ? myR[lane + 448] : 0ull;
        sort256(w0, w1, w2, w3, lane);
        merge256(v0, v1, v2, v3, w0, w1, w2, w3, lane);
    }

    // flush sorted top-256 straight from registers
    u64* seg = top + ((size_t)b * NLIST + blk) * KMAX;
    seg[lane]       = v0;
    seg[lane + 64]  = v1;
    seg[lane + 128] = v2;
    seg[lane + 192] = v3;
}

// ---------------------------------------------------------------------------
// K2a: ONE WAVE per block. Register-merge 4 sorted lists -> 1 (two merge256 +
// final merge256). 128 lists/image -> 32.
// ---------------------------------------------------------------------------
__global__ __launch_bounds__(64)
void merge4_kernel(const u64* __restrict__ top,
                   u64* __restrict__ mid) {
    const int o    = blockIdx.x;         // 0..31
    const int b    = blockIdx.y;
    const int lane = threadIdx.x;

    const u64* L = top + ((size_t)b * NLIST + o * 4) * KMAX;

    u64 a0 = L[lane],            a1 = L[lane + 64],
        a2 = L[lane + 128],      a3 = L[lane + 192];
    {
        const u64 w0 = L[KMAX + lane],       w1 = L[KMAX + lane + 64],
                  w2 = L[KMAX + lane + 128], w3 = L[KMAX + lane + 192];
        merge256(a0, a1, a2, a3, w0, w1, w2, w3, lane);
    }
    u64 c0 = L[2 * KMAX + lane],        c1 = L[2 * KMAX + lane + 64],
        c2 = L[2 * KMAX + lane + 128],  c3 = L[2 * KMAX + lane + 192];
    {
        const u64 w0 = L[3 * KMAX + lane],       w1 = L[3 * KMAX + lane + 64],
                  w2 = L[3 * KMAX + lane + 128], w3 = L[3 * KMAX + lane + 192];
        merge256(c0, c1, c2, c3, w0, w1, w2, w3, lane);
    }
    merge256(a0, a1, a2, a3, c0, c1, c2, c3, lane);

    u64* out = mid + ((size_t)b * NMID + o) * KMAX;
    out[lane]       = a0;
    out[lane + 64]  = a1;
    out[lane + 128] = a2;
    out[lane + 192] = a3;
}

// ---------------------------------------------------------------------------
// K3 (tail): 1 block/image x 512 threads. 32 sorted-desc 256-lists ->
// 5 rounds of pairwise top-256 merge (D[i] = max(A[i], B[255-i]) + 8-phase
// bitonic clean). Final list = exact sorted global top-256 -> ROI epilogue.
// ---------------------------------------------------------------------------
__global__ __launch_bounds__(TPB2)
void tail_kernel(const u64* __restrict__ mid,
                 const float* __restrict__ scale,
                 const float* __restrict__ unc,
                 const int* __restrict__ imh,
                 const int* __restrict__ imw,
                 float* __restrict__ rois,
                 float* __restrict__ scoresOut,
                 float* __restrict__ validOut) {
    const int b   = blockIdx.x;
    const int tid = threadIdx.x;

    __shared__ u64 bufA[NMID * KMAX];        // 64 KB
    __shared__ u64 bufB[(NMID / 2) * KMAX];  // 32 KB

    const u64* tb = mid + (size_t)b * NMID * KMAX;
    for (int i = tid; i < NMID * KMAX; i += TPB2) bufA[i] = tb[i];
    __syncthreads();

    u64* src = bufA;
    u64* dst = bufB;
    int nl = NMID;
    while (nl > 1) {
        const int half = nl >> 1;
        const int E = half * KMAX;
        for (int p = tid; p < E; p += TPB2) {
            const int h = p >> 8;
            const int i = p & (KMAX - 1);
            const u64 a = src[(2 * h) * KMAX + i];
            const u64 c = src[(2 * h + 1) * KMAX + (KMAX - 1 - i)];
            dst[p] = (a > c) ? a : c;
        }
        __syncthreads();
        for (int j = KMAX >> 1; j > 0; j >>= 1) {
            for (int p = tid; p < (E >> 1); p += TPB2) {
                const int i   = ((p & ~(j - 1)) << 1) | (p & (j - 1));
                const int ixj = i | j;
                const u64 a = dst[i];
                const u64 c = dst[ixj];
                if (a < c) { dst[i] = c; dst[ixj] = a; }
            }
            __syncthreads();
        }
        u64* t = src; src = dst; dst = t;
        nl = half;
    }

    if (tid < KMAX) {
        const u64 k = src[tid];
        const float value = __uint_as_float((unsigned)(k >> 32));
        const bool valid  = (k != 0ull) && (value > 0.0f);

        float r0 = 0.f, r1 = 0.f, r2 = 0.f, r3 = 0.f, r4 = 0.f, sv = 0.f, vv = 0.f;
        if (valid) {
            const unsigned idx = ~(unsigned)(k & 0xFFFFFFFFull);
            const int y = (int)(idx / IMW);
            const int x = (int)(idx % IMW);
            const float cx = ((float)x + 0.5f) * 4.0f;
            const float cy = ((float)y + 0.5f) * 4.0f;
            const float sg = scale[(size_t)b * IMH * IMW + idx];
            const float uu = unc[(size_t)b * IMH * IMW + idx];
            const float su = sigmoidf_(uu);
            float side = 32.0f + sigmoidf_(sg) * (512.0f - 32.0f);
            side = side * (1.0f + 0.25f * su);
            const float half2 = side * 0.5f;
            const float fw = (float)imw[0];
            const float fh = (float)imh[0];
            r0 = (float)b;
            r1 = fminf(fmaxf(cx - half2, 0.0f), fw - 1.0f);
            r2 = fminf(fmaxf(cy - half2, 0.0f), fh - 1.0f);
            r3 = fminf(fmaxf(cx + half2, 1.0f), fw);
            r4 = fminf(fmaxf(cy + half2, 1.0f), fh);
            sv = value;
            vv = 1.0f;
        }
        float* roiP = rois + ((size_t)b * KMAX + tid) * 5;
        roiP[0] = r0; roiP[1] = r1; roiP[2] = r2; roiP[3] = r3; roiP[4] = r4;
        scoresOut[b * KMAX + tid] = sv;
        validOut[b * KMAX + tid]  = vv;
    }
}

extern "C" void kernel_launch(void* const* d_in, const int* in_sizes, int n_in,
                              void* d_out, int out_size, void* d_ws, size_t ws_size,
                              hipStream_t stream) {
    const float* route = (const float*)d_in[0];
    const float* scale = (const float*)d_in[1];
    const float* unc   = (const float*)d_in[2];
    const int*   imh   = (const int*)d_in[3];
    const int*   imw   = (const int*)d_in[4];

    // ws layout: [top B*128*256 u64 = 8MB][mid B*32*256 u64 = 2MB]
    u64* top = (u64*)d_ws;
    u64* mid = top + (size_t)BATCH * NLIST * KMAX;

    float* rois      = (float*)d_out;                       // [B, 256, 5]
    float* scoresOut = rois + (size_t)BATCH * KMAX * 5;     // [B, 256]
    float* validOut  = scoresOut + (size_t)BATCH * KMAX;    // [B, 256]

    dim3 grid1(NBLKX, IMH / RPW, BATCH);   // 2 x 64 x 32 = 4096 wave-blocks
    score_nms_kernel<<<grid1, 64, 0, stream>>>(route, unc, top);

    dim3 grid2(NMID, BATCH);               // 32 x 32 wave-blocks
    merge4_kernel<<<grid2, 64, 0, stream>>>(top, mid);

    tail_kernel<<<BATCH, TPB2, 0, stream>>>(mid, scale, unc,
                                            imh, imw, rois, scoresOut, validOut);
}

// Round 20
// 63.434 us; speedup vs baseline: 1.1428x; 1.0185x over previous
//
#include <hip/hip_runtime.h>
#include <cstdint>
#include <cstddef>

#define BATCH 32
#define IMH 512
#define IMW 512
#define KMAX 256

// K1: ONE wave per block handles a 256x16 strip-PAIR (two 256x8 strips).
#define RPW 8
#define NBLKX 2
#define NYG (IMH / (2 * RPW))          // 32 y-groups
#define NL1 (NBLKX * NYG)              // 64 lists/image out of K1
#define NMID 16                        // lists/image after merge4
#define WCAP 512                       // worst-case strict maxima in 256x8

#define TPB2 512                       // tail threads (8 waves)

typedef unsigned long long u64;

__device__ __forceinline__ float sigmoidf_(float x) {
    return 1.0f / (1.0f + expf(-x));
}
__device__ __forceinline__ float scoref_(float r, float u) {
    const float sg = sigmoidf_(r);
    return sg * sg * (1.0f - 0.35f * sigmoidf_(u));
}

// ---------------------------------------------------------------------------
// Register-resident wave bitonic sort (folded compare-exchange, R19-verified).
// SHF2 interleaves two independent networks to double ILP on the dependent
// shuffle chain (the LDS-pipe latency of chain A hides under chain B).
// ---------------------------------------------------------------------------
#define SHF(v, jj, dm) do {                                         \
    const u64 o_ = __shfl_xor((v), (jj), 64);                       \
    const bool take_ = ((((lane & (jj)) == 0) == (dm)) == ((v) < o_)); \
    (v) = take_ ? o_ : (v);                                         \
} while (0)

#define SHF2(v, u, jj, dm) do {                                     \
    const u64 ov_ = __shfl_xor((v), (jj), 64);                      \
    const u64 ou_ = __shfl_xor((u), (jj), 64);                      \
    const bool dir_ = (((lane & (jj)) == 0) == (dm));               \
    const bool tv_ = (dir_ == ((v) < ov_));                         \
    const bool tu_ = (dir_ == ((u) < ou_));                         \
    (v) = tv_ ? ov_ : (v);                                          \
    (u) = tu_ ? ou_ : (u);                                          \
} while (0)

#define RMAX(a, b) do {                                             \
    const u64 hi_ = ((a) > (b)) ? (a) : (b);                        \
    const u64 lo_ = ((a) > (b)) ? (b) : (a);                        \
    (a) = hi_; (b) = lo_;                                           \
} while (0)

#define RMIN(a, b) do {                                             \
    const u64 hi_ = ((a) > (b)) ? (a) : (b);                        \
    const u64 lo_ = ((a) > (b)) ? (b) : (a);                        \
    (a) = lo_; (b) = hi_;                                           \
} while (0)

__device__ __forceinline__ void clean256(u64& v0, u64& v1, u64& v2, u64& v3,
                                         const int lane) {
    RMAX(v0, v2); RMAX(v1, v3);
    RMAX(v0, v1); RMAX(v2, v3);
    #pragma unroll
    for (int j = 32; j > 0; j >>= 1) {
        SHF(v0, j, true); SHF(v1, j, true); SHF(v2, j, true); SHF(v3, j, true);
    }
}

__device__ __forceinline__ void sort256(u64& v0, u64& v1, u64& v2, u64& v3,
                                        const int lane) {
    #pragma unroll
    for (int k = 2; k <= 32; k <<= 1) {
        #pragma unroll
        for (int j = k >> 1; j > 0; j >>= 1) {
            const bool dm = ((lane & k) == 0);
            SHF(v0, j, dm); SHF(v1, j, dm); SHF(v2, j, dm); SHF(v3, j, dm);
        }
    }
    #pragma unroll
    for (int j = 32; j > 0; j >>= 1) {
        SHF(v0, j, true); SHF(v1, j, false); SHF(v2, j, true); SHF(v3, j, false);
    }
    RMAX(v0, v1); RMIN(v2, v3);
    #pragma unroll
    for (int j = 32; j > 0; j >>= 1) {
        SHF(v0, j, true); SHF(v1, j, true); SHF(v2, j, false); SHF(v3, j, false);
    }
    clean256(v0, v1, v2, v3, lane);
}

// two interleaved sort256 networks (independent chains)
__device__ __forceinline__ void sort256x2(u64& v0, u64& v1, u64& v2, u64& v3,
                                          u64& u0, u64& u1, u64& u2, u64& u3,
                                          const int lane) {
    #pragma unroll
    for (int k = 2; k <= 32; k <<= 1) {
        #pragma unroll
        for (int j = k >> 1; j > 0; j >>= 1) {
            const bool dm = ((lane & k) == 0);
            SHF2(v0, u0, j, dm); SHF2(v1, u1, j, dm);
            SHF2(v2, u2, j, dm); SHF2(v3, u3, j, dm);
        }
    }
    #pragma unroll
    for (int j = 32; j > 0; j >>= 1) {
        SHF2(v0, u0, j, true); SHF2(v1, u1, j, false);
        SHF2(v2, u2, j, true); SHF2(v3, u3, j, false);
    }
    RMAX(v0, v1); RMIN(v2, v3);
    RMAX(u0, u1); RMIN(u2, u3);
    #pragma unroll
    for (int j = 32; j > 0; j >>= 1) {
        SHF2(v0, u0, j, true); SHF2(v1, u1, j, true);
        SHF2(v2, u2, j, false); SHF2(v3, u3, j, false);
    }
    // clean
    RMAX(v0, v2); RMAX(v1, v3); RMAX(u0, u2); RMAX(u1, u3);
    RMAX(v0, v1); RMAX(v2, v3); RMAX(u0, u1); RMAX(u2, u3);
    #pragma unroll
    for (int j = 32; j > 0; j >>= 1) {
        SHF2(v0, u0, j, true); SHF2(v1, u1, j, true);
        SHF2(v2, u2, j, true); SHF2(v3, u3, j, true);
    }
}

__device__ __forceinline__ void merge256(u64& v0, u64& v1, u64& v2, u64& v3,
                                         u64 w0, u64 w1, u64 w2, u64 w3,
                                         const int lane) {
    const int rl = 63 ^ lane;
    const u64 b0 = __shfl(w3, rl, 64);
    const u64 b1 = __shfl(w2, rl, 64);
    const u64 b2 = __shfl(w1, rl, 64);
    const u64 b3 = __shfl(w0, rl, 64);
    v0 = (v0 > b0) ? v0 : b0;
    v1 = (v1 > b1) ? v1 : b1;
    v2 = (v2 > b2) ? v2 : b2;
    v3 = (v3 > b3) ? v3 : b3;
    clean256(v0, v1, v2, v3, lane);
}

// ---------------------------------------------------------------------------
// K1: ONE WAVE per block, ZERO barriers, 256x16 strip-pair. Stream strip A
// then strip B (LDS append, same-wave RAW), two INTERLEAVED register sorts,
// rare >256 overflow handled sequentially, in-register merge256(A,B), write
// the pair's sorted top-256. Tournament property preserved.
// key = (score_bits<<32) | ~idx -> unsigned desc == (score desc, idx asc).
// ---------------------------------------------------------------------------
__global__ __launch_bounds__(64)
void score_nms_kernel(const float* __restrict__ route,
                      const float* __restrict__ unc,
                      u64* __restrict__ top) {
    const int b    = blockIdx.z;
    const int lane = threadIdx.x;
    const int x0   = blockIdx.x * 256 + lane * 4;
    const int list = blockIdx.y * NBLKX + blockIdx.x;

    __shared__ u64 myR[2 * WCAP];        // 8 KB: region per strip

    const float* rB = route + (size_t)b * IMH * IMW;
    const float* uB = unc   + (size_t)b * IMH * IMW;

    int ex = -1;
    if (lane == 0)       ex = x0 - 1;
    else if (lane == 63) ex = x0 + 4;
    const bool eAct = (ex >= 0 && ex < IMW);

    const u64 laneMaskLt = (1ull << lane) - 1ull;
    int wcntA = 0, wcntB = 0;

    #pragma unroll
    for (int s = 0; s < 2; ++s) {
        const int y0 = (blockIdx.y * 2 + s) * RPW;
        u64* reg = myR + s * WCAP;
        int wcnt = 0;

        float sP[4], hP1[4], hP2[4];
        #pragma unroll
        for (int j = 0; j < 4; ++j) { sP[j] = -INFINITY; hP1[j] = -INFINITY; hP2[j] = -INFINITY; }

        const int ylast = y0 + RPW;
        bool v = (y0 - 1 >= 0);
        float4 r4, u4; float er = 0.f, eu = 0.f;
        if (v) {
            r4 = *(const float4*)(rB + (size_t)(y0 - 1) * IMW + x0);
            u4 = *(const float4*)(uB + (size_t)(y0 - 1) * IMW + x0);
            if (eAct) { er = rB[(size_t)(y0 - 1) * IMW + ex]; eu = uB[(size_t)(y0 - 1) * IMW + ex]; }
        }

        for (int y = y0 - 1; y <= ylast; ++y) {
            const int yn = y + 1;
            const bool vn = (yn <= ylast) && (yn < IMH);
            float4 r4n, u4n; float ern = 0.f, eun = 0.f;
            if (vn) {
                r4n = *(const float4*)(rB + (size_t)yn * IMW + x0);
                u4n = *(const float4*)(uB + (size_t)yn * IMW + x0);
                if (eAct) { ern = rB[(size_t)yn * IMW + ex]; eun = uB[(size_t)yn * IMW + ex]; }
            }

            float sC[4], hmC[4];
            float es = -INFINITY;
            if (v && eAct) es = scoref_(er, eu);
            if (v) {
                sC[0] = scoref_(r4.x, u4.x);
                sC[1] = scoref_(r4.y, u4.y);
                sC[2] = scoref_(r4.z, u4.z);
                sC[3] = scoref_(r4.w, u4.w);
            } else {
                sC[0] = sC[1] = sC[2] = sC[3] = -INFINITY;
            }
            float lft = __shfl_up(sC[3], 1, 64);
            if (lane == 0) lft = es;
            float rgt = __shfl_down(sC[0], 1, 64);
            if (lane == 63) rgt = es;
            if (v) {
                hmC[0] = fmaxf(fmaxf(lft,   sC[0]), sC[1]);
                hmC[1] = fmaxf(fmaxf(sC[0], sC[1]), sC[2]);
                hmC[2] = fmaxf(fmaxf(sC[1], sC[2]), sC[3]);
                hmC[3] = fmaxf(fmaxf(sC[2], sC[3]), rgt);
            } else {
                hmC[0] = hmC[1] = hmC[2] = hmC[3] = -INFINITY;
            }

            if (y >= y0 + 1) {
                const int yo = y - 1;
                bool p[4]; int cntT = 0;
                #pragma unroll
                for (int j = 0; j < 4; ++j) {
                    const float m9 = fmaxf(fmaxf(hP2[j], hP1[j]), hmC[j]);
                    p[j] = (sP[j] >= m9);
                    cntT += p[j] ? 1 : 0;
                }
                const u64 B0 = __ballot(cntT & 1);
                const u64 B1 = __ballot(cntT & 2);
                const u64 B2 = __ballot(cntT & 4);
                const int total = __popcll(B0) + 2 * __popcll(B1) + 4 * __popcll(B2);
                if (total > 0) {
                    const int prefix = __popcll(B0 & laneMaskLt) + 2 * __popcll(B1 & laneMaskLt)
                                     + 4 * __popcll(B2 & laneMaskLt);
                    int mb = wcnt + prefix;
                    #pragma unroll
                    for (int j = 0; j < 4; ++j) {
                        if (p[j]) {
                            const unsigned idx = (unsigned)(yo * IMW + (x0 + j));
                            const u64 key = ((u64)__float_as_uint(sP[j]) << 32) | (unsigned)(~idx);
                            if (mb < WCAP) reg[mb] = key;
                            ++mb;
                        }
                    }
                    wcnt += total;
                }
            }

            #pragma unroll
            for (int j = 0; j < 4; ++j) { hP2[j] = hP1[j]; hP1[j] = hmC[j]; sP[j] = sC[j]; }
            r4 = r4n; u4 = u4n; er = ern; eu = eun; v = vn;
        }

        if (s == 0) wcntA = wcnt; else wcntB = wcnt;
    }

    // ---- two interleaved register sorts (no barrier: same-wave RAW) ----
    const int mA = (wcntA < WCAP) ? wcntA : WCAP;
    const int mB = (wcntB < WCAP) ? wcntB : WCAP;
    u64 a0, a1, a2, a3, c0, c1, c2, c3;
    a0 = (lane       < mA) ? myR[lane]       : 0ull;
    a1 = (lane + 64  < mA) ? myR[lane + 64]  : 0ull;
    a2 = (lane + 128 < mA) ? myR[lane + 128] : 0ull;
    a3 = (lane + 192 < mA) ? myR[lane + 192] : 0ull;
    c0 = (lane       < mB) ? myR[WCAP + lane]       : 0ull;
    c1 = (lane + 64  < mB) ? myR[WCAP + lane + 64]  : 0ull;
    c2 = (lane + 128 < mB) ? myR[WCAP + lane + 128] : 0ull;
    c3 = (lane + 192 < mB) ? myR[WCAP + lane + 192] : 0ull;
    sort256x2(a0, a1, a2, a3, c0, c1, c2, c3, lane);

    if (mA > 256) {     // rare overflow: sort remainder and merge
        u64 w0, w1, w2, w3;
        w0 = (lane + 256 < mA) ? myR[lane + 256] : 0ull;
        w1 = (lane + 320 < mA) ? myR[lane + 320] : 0ull;
        w2 = (lane + 384 < mA) ? myR[lane + 384] : 0ull;
        w3 = (lane + 448 < mA) ? myR[lane + 448] : 0ull;
        sort256(w0, w1, w2, w3, lane);
        merge256(a0, a1, a2, a3, w0, w1, w2, w3, lane);
    }
    if (mB > 256) {
        u64 w0, w1, w2, w3;
        w0 = (lane + 256 < mB) ? myR[WCAP + lane + 256] : 0ull;
        w1 = (lane + 320 < mB) ? myR[WCAP + lane + 320] : 0ull;
        w2 = (lane + 384 < mB) ? myR[WCAP + lane + 384] : 0ull;
        w3 = (lane + 448 < mB) ? myR[WCAP + lane + 448] : 0ull;
        sort256(w0, w1, w2, w3, lane);
        merge256(c0, c1, c2, c3, w0, w1, w2, w3, lane);
    }

    // merge the two strips' top-256 -> pair top-256
    merge256(a0, a1, a2, a3, c0, c1, c2, c3, lane);

    // flush sorted top-256 straight from registers
    u64* seg = top + ((size_t)b * NL1 + list) * KMAX;
    seg[lane]       = a0;
    seg[lane + 64]  = a1;
    seg[lane + 128] = a2;
    seg[lane + 192] = a3;
}

// ---------------------------------------------------------------------------
// K2a: ONE WAVE per block. Register-merge 4 sorted lists -> 1.
// 64 lists/image -> 16.
// ---------------------------------------------------------------------------
__global__ __launch_bounds__(64)
void merge4_kernel(const u64* __restrict__ top,
                   u64* __restrict__ mid) {
    const int o    = blockIdx.x;         // 0..NMID-1
    const int b    = blockIdx.y;
    const int lane = threadIdx.x;

    const u64* L = top + ((size_t)b * NL1 + o * 4) * KMAX;

    u64 a0 = L[lane],            a1 = L[lane + 64],
        a2 = L[lane + 128],      a3 = L[lane + 192];
    {
        const u64 w0 = L[KMAX + lane],       w1 = L[KMAX + lane + 64],
                  w2 = L[KMAX + lane + 128], w3 = L[KMAX + lane + 192];
        merge256(a0, a1, a2, a3, w0, w1, w2, w3, lane);
    }
    u64 c0 = L[2 * KMAX + lane],        c1 = L[2 * KMAX + lane + 64],
        c2 = L[2 * KMAX + lane + 128],  c3 = L[2 * KMAX + lane + 192];
    {
        const u64 w0 = L[3 * KMAX + lane],       w1 = L[3 * KMAX + lane + 64],
                  w2 = L[3 * KMAX + lane + 128], w3 = L[3 * KMAX + lane + 192];
        merge256(c0, c1, c2, c3, w0, w1, w2, w3, lane);
    }
    merge256(a0, a1, a2, a3, c0, c1, c2, c3, lane);

    u64* out = mid + ((size_t)b * NMID + o) * KMAX;
    out[lane]       = a0;
    out[lane + 64]  = a1;
    out[lane + 128] = a2;
    out[lane + 192] = a3;
}

// ---------------------------------------------------------------------------
// K3 (tail): 1 block/image x 512 threads. 16 sorted-desc 256-lists ->
// 4 rounds of pairwise top-256 merge (D[i] = max(A[i], B[255-i]) + 8-phase
// bitonic clean). Final list = exact sorted global top-256 -> ROI epilogue.
// ---------------------------------------------------------------------------
__global__ __launch_bounds__(TPB2)
void tail_kernel(const u64* __restrict__ mid,
                 const float* __restrict__ scale,
                 const float* __restrict__ unc,
                 const int* __restrict__ imh,
                 const int* __restrict__ imw,
                 float* __restrict__ rois,
                 float* __restrict__ scoresOut,
                 float* __restrict__ validOut) {
    const int b   = blockIdx.x;
    const int tid = threadIdx.x;

    __shared__ u64 bufA[NMID * KMAX];        // 32 KB
    __shared__ u64 bufB[(NMID / 2) * KMAX];  // 16 KB

    const u64* tb = mid + (size_t)b * NMID * KMAX;
    for (int i = tid; i < NMID * KMAX; i += TPB2) bufA[i] = tb[i];
    __syncthreads();

    u64* src = bufA;
    u64* dst = bufB;
    int nl = NMID;
    while (nl > 1) {
        const int half = nl >> 1;
        const int E = half * KMAX;
        for (int p = tid; p < E; p += TPB2) {
            const int h = p >> 8;
            const int i = p & (KMAX - 1);
            const u64 a = src[(2 * h) * KMAX + i];
            const u64 c = src[(2 * h + 1) * KMAX + (KMAX - 1 - i)];
            dst[p] = (a > c) ? a : c;
        }
        __syncthreads();
        for (int j = KMAX >> 1; j > 0; j >>= 1) {
            for (int p = tid; p < (E >> 1); p += TPB2) {
                const int i   = ((p & ~(j - 1)) << 1) | (p & (j - 1));
                const int ixj = i | j;
                const u64 a = dst[i];
                const u64 c = dst[ixj];
                if (a < c) { dst[i] = c; dst[ixj] = a; }
            }
            __syncthreads();
        }
        u64* t = src; src = dst; dst = t;
        nl = half;
    }

    if (tid < KMAX) {
        const u64 k = src[tid];
        const float value = __uint_as_float((unsigned)(k >> 32));
        const bool valid  = (k != 0ull) && (value > 0.0f);

        float r0 = 0.f, r1 = 0.f, r2 = 0.f, r3 = 0.f, r4 = 0.f, sv = 0.f, vv = 0.f;
        if (valid) {
            const unsigned idx = ~(unsigned)(k & 0xFFFFFFFFull);
            const int y = (int)(idx / IMW);
            const int x = (int)(idx % IMW);
            const float cx = ((float)x + 0.5f) * 4.0f;
            const float cy = ((float)y + 0.5f) * 4.0f;
            const float sg = scale[(size_t)b * IMH * IMW + idx];
            const float uu = unc[(size_t)b * IMH * IMW + idx];
            const float su = sigmoidf_(uu);
            float side = 32.0f + sigmoidf_(sg) * (512.0f - 32.0f);
            side = side * (1.0f + 0.25f * su);
            const float half2 = side * 0.5f;
            const float fw = (float)imw[0];
            const float fh = (float)imh[0];
            r0 = (float)b;
            r1 = fminf(fmaxf(cx - half2, 0.0f), fw - 1.0f);
            r2 = fminf(fmaxf(cy - half2, 0.0f), fh - 1.0f);
            r3 = fminf(fmaxf(cx + half2, 1.0f), fw);
            r4 = fminf(fmaxf(cy + half2, 1.0f), fh);
            sv = value;
            vv = 1.0f;
        }
        float* roiP = rois + ((size_t)b * KMAX + tid) * 5;
        roiP[0] = r0; roiP[1] = r1; roiP[2] = r2; roiP[3] = r3; roiP[4] = r4;
        scoresOut[b * KMAX + tid] = sv;
        validOut[b * KMAX + tid]  = vv;
    }
}

extern "C" void kernel_launch(void* const* d_in, const int* in_sizes, int n_in,
                              void* d_out, int out_size, void* d_ws, size_t ws_size,
                              hipStream_t stream) {
    const float* route = (const float*)d_in[0];
    const float* scale = (const float*)d_in[1];
    const float* unc   = (const float*)d_in[2];
    const int*   imh   = (const int*)d_in[3];
    const int*   imw   = (const int*)d_in[4];

    // ws layout: [top B*64*256 u64 = 4MB][mid B*16*256 u64 = 1MB]
    u64* top = (u64*)d_ws;
    u64* mid = top + (size_t)BATCH * NL1 * KMAX;

    float* rois      = (float*)d_out;                       // [B, 256, 5]
    float* scoresOut = rois + (size_t)BATCH * KMAX * 5;     // [B, 256]
    float* validOut  = scoresOut + (size_t)BATCH * KMAX;    // [B, 256]

    dim3 grid1(NBLKX, NYG, BATCH);         // 2 x 32 x 32 = 2048 wave-blocks
    score_nms_kernel<<<grid1, 64, 0, stream>>>(route, unc, top);

    dim3 grid2(NMID, BATCH);               // 16 x 32 wave-blocks
    merge4_kernel<<<grid2, 64, 0, stream>>>(top, mid);

    tail_kernel<<<BATCH, TPB2, 0, stream>>>(mid, scale, unc,
                                            imh, imw, rois, scoresOut, validOut);
}

// Round 21
// 60.596 us; speedup vs baseline: 1.1963x; 1.0468x over previous
//
#include <hip/hip_runtime.h>
#include <cstdint>
#include <cstddef>

#define BATCH 32
#define IMH 512
#define IMW 512
#define KMAX 256

// K1: ONE wave per block handles a 256x4 strip.
#define RPW 4
#define NBLKX 2
#define NYG (IMH / RPW)                // 128 y-groups
#define NL1 (NBLKX * NYG)              // 256 lists/image out of K1
#define NM1 (NL1 / 4)                  // 64 after merge4 round 1
#define NMID (NM1 / 4)                 // 16 after merge4 round 2
#define WCAP 256                       // worst-case strict maxima in 256x4 = 256

#define TPB2 512                       // tail threads (8 waves)

typedef unsigned long long u64;

__device__ __forceinline__ float sigmoidf_(float x) {
    return 1.0f / (1.0f + expf(-x));
}
__device__ __forceinline__ float scoref_(float r, float u) {
    const float sg = sigmoidf_(r);
    return sg * sg * (1.0f - 0.35f * sigmoidf_(u));
}

// ---------------------------------------------------------------------------
// Register-resident wave bitonic sort (folded compare-exchange, R19-verified
// network). sort128 = same construction on 2 regs (N=128).
// ---------------------------------------------------------------------------
#define SHF(v, jj, dm) do {                                         \
    const u64 o_ = __shfl_xor((v), (jj), 64);                       \
    const bool take_ = ((((lane & (jj)) == 0) == (dm)) == ((v) < o_)); \
    (v) = take_ ? o_ : (v);                                         \
} while (0)

#define RMAX(a, b) do {                                             \
    const u64 hi_ = ((a) > (b)) ? (a) : (b);                        \
    const u64 lo_ = ((a) > (b)) ? (b) : (a);                        \
    (a) = hi_; (b) = lo_;                                           \
} while (0)

#define RMIN(a, b) do {                                             \
    const u64 hi_ = ((a) > (b)) ? (a) : (b);                        \
    const u64 lo_ = ((a) > (b)) ? (b) : (a);                        \
    (a) = lo_; (b) = hi_;                                           \
} while (0)

__device__ __forceinline__ void clean256(u64& v0, u64& v1, u64& v2, u64& v3,
                                         const int lane) {
    RMAX(v0, v2); RMAX(v1, v3);
    RMAX(v0, v1); RMAX(v2, v3);
    #pragma unroll
    for (int j = 32; j > 0; j >>= 1) {
        SHF(v0, j, true); SHF(v1, j, true); SHF(v2, j, true); SHF(v3, j, true);
    }
}

__device__ __forceinline__ void sort256(u64& v0, u64& v1, u64& v2, u64& v3,
                                        const int lane) {
    #pragma unroll
    for (int k = 2; k <= 32; k <<= 1) {
        #pragma unroll
        for (int j = k >> 1; j > 0; j >>= 1) {
            const bool dm = ((lane & k) == 0);
            SHF(v0, j, dm); SHF(v1, j, dm); SHF(v2, j, dm); SHF(v3, j, dm);
        }
    }
    #pragma unroll
    for (int j = 32; j > 0; j >>= 1) {
        SHF(v0, j, true); SHF(v1, j, false); SHF(v2, j, true); SHF(v3, j, false);
    }
    RMAX(v0, v1); RMIN(v2, v3);
    #pragma unroll
    for (int j = 32; j > 0; j >>= 1) {
        SHF(v0, j, true); SHF(v1, j, true); SHF(v2, j, false); SHF(v3, j, false);
    }
    clean256(v0, v1, v2, v3, lane);
}

// N=128 over 2 regs (e = r*64 + lane), descending
__device__ __forceinline__ void sort128(u64& v0, u64& v1, const int lane) {
    #pragma unroll
    for (int k = 2; k <= 32; k <<= 1) {
        #pragma unroll
        for (int j = k >> 1; j > 0; j >>= 1) {
            const bool dm = ((lane & k) == 0);
            SHF(v0, j, dm); SHF(v1, j, dm);
        }
    }
    // k=64: dir = (r even)
    #pragma unroll
    for (int j = 32; j > 0; j >>= 1) {
        SHF(v0, j, true); SHF(v1, j, false);
    }
    // k=128 (final clean): j=64 reg phase + shuffles, all dir=max
    RMAX(v0, v1);
    #pragma unroll
    for (int j = 32; j > 0; j >>= 1) {
        SHF(v0, j, true); SHF(v1, j, true);
    }
}

__device__ __forceinline__ void merge256(u64& v0, u64& v1, u64& v2, u64& v3,
                                         u64 w0, u64 w1, u64 w2, u64 w3,
                                         const int lane) {
    const int rl = 63 ^ lane;
    const u64 b0 = __shfl(w3, rl, 64);
    const u64 b1 = __shfl(w2, rl, 64);
    const u64 b2 = __shfl(w1, rl, 64);
    const u64 b3 = __shfl(w0, rl, 64);
    v0 = (v0 > b0) ? v0 : b0;
    v1 = (v1 > b1) ? v1 : b1;
    v2 = (v2 > b2) ? v2 : b2;
    v3 = (v3 > b3) ? v3 : b3;
    clean256(v0, v1, v2, v3, lane);
}

// ---------------------------------------------------------------------------
// K1: ONE WAVE per block, ZERO barriers, 256x4 strip. Stream score+NMS,
// append to the wave's LDS region (same-wave RAW), register-sort (128 fast
// path / 256 full — worst case in a 256x4 strip is exactly 256), write the
// sorted top-256 (zero-padded) straight from registers. Tournament property:
// any global top-256 key is in its strip's top-256.
// key = (score_bits<<32) | ~idx -> unsigned desc == (score desc, idx asc),
// matching lax.top_k's stable tie-break.
// ---------------------------------------------------------------------------
__global__ __launch_bounds__(64)
void score_nms_kernel(const float* __restrict__ route,
                      const float* __restrict__ unc,
                      u64* __restrict__ top) {
    const int b    = blockIdx.z;
    const int lane = threadIdx.x;
    const int y0   = blockIdx.y * RPW;
    const int x0   = blockIdx.x * 256 + lane * 4;
    const int list = blockIdx.y * NBLKX + blockIdx.x;

    __shared__ u64 myR[WCAP];            // 2 KB

    const float* rB = route + (size_t)b * IMH * IMW;
    const float* uB = unc   + (size_t)b * IMH * IMW;

    int ex = -1;
    if (lane == 0)       ex = x0 - 1;
    else if (lane == 63) ex = x0 + 4;
    const bool eAct = (ex >= 0 && ex < IMW);

    const u64 laneMaskLt = (1ull << lane) - 1ull;
    int wcnt = 0;

    float sP[4], hP1[4], hP2[4];
    #pragma unroll
    for (int j = 0; j < 4; ++j) { sP[j] = -INFINITY; hP1[j] = -INFINITY; hP2[j] = -INFINITY; }

    const int ylast = y0 + RPW;
    bool v = (y0 - 1 >= 0);
    float4 r4, u4; float er = 0.f, eu = 0.f;
    if (v) {
        r4 = *(const float4*)(rB + (size_t)(y0 - 1) * IMW + x0);
        u4 = *(const float4*)(uB + (size_t)(y0 - 1) * IMW + x0);
        if (eAct) { er = rB[(size_t)(y0 - 1) * IMW + ex]; eu = uB[(size_t)(y0 - 1) * IMW + ex]; }
    }

    for (int y = y0 - 1; y <= ylast; ++y) {
        const int yn = y + 1;
        const bool vn = (yn <= ylast) && (yn < IMH);
        float4 r4n, u4n; float ern = 0.f, eun = 0.f;
        if (vn) {
            r4n = *(const float4*)(rB + (size_t)yn * IMW + x0);
            u4n = *(const float4*)(uB + (size_t)yn * IMW + x0);
            if (eAct) { ern = rB[(size_t)yn * IMW + ex]; eun = uB[(size_t)yn * IMW + ex]; }
        }

        float sC[4], hmC[4];
        float es = -INFINITY;
        if (v && eAct) es = scoref_(er, eu);
        if (v) {
            sC[0] = scoref_(r4.x, u4.x);
            sC[1] = scoref_(r4.y, u4.y);
            sC[2] = scoref_(r4.z, u4.z);
            sC[3] = scoref_(r4.w, u4.w);
        } else {
            sC[0] = sC[1] = sC[2] = sC[3] = -INFINITY;
        }
        float lft = __shfl_up(sC[3], 1, 64);
        if (lane == 0) lft = es;
        float rgt = __shfl_down(sC[0], 1, 64);
        if (lane == 63) rgt = es;
        if (v) {
            hmC[0] = fmaxf(fmaxf(lft,   sC[0]), sC[1]);
            hmC[1] = fmaxf(fmaxf(sC[0], sC[1]), sC[2]);
            hmC[2] = fmaxf(fmaxf(sC[1], sC[2]), sC[3]);
            hmC[3] = fmaxf(fmaxf(sC[2], sC[3]), rgt);
        } else {
            hmC[0] = hmC[1] = hmC[2] = hmC[3] = -INFINITY;
        }

        if (y >= y0 + 1) {
            const int yo = y - 1;
            bool p[4]; int cntT = 0;
            #pragma unroll
            for (int j = 0; j < 4; ++j) {
                const float m9 = fmaxf(fmaxf(hP2[j], hP1[j]), hmC[j]);
                p[j] = (sP[j] >= m9);
                cntT += p[j] ? 1 : 0;
            }
            const u64 B0 = __ballot(cntT & 1);
            const u64 B1 = __ballot(cntT & 2);
            const u64 B2 = __ballot(cntT & 4);
            const int total = __popcll(B0) + 2 * __popcll(B1) + 4 * __popcll(B2);
            if (total > 0) {
                const int prefix = __popcll(B0 & laneMaskLt) + 2 * __popcll(B1 & laneMaskLt)
                                 + 4 * __popcll(B2 & laneMaskLt);
                int mb = wcnt + prefix;
                #pragma unroll
                for (int j = 0; j < 4; ++j) {
                    if (p[j]) {
                        const unsigned idx = (unsigned)(yo * IMW + (x0 + j));
                        const u64 key = ((u64)__float_as_uint(sP[j]) << 32) | (unsigned)(~idx);
                        if (mb < WCAP) myR[mb] = key;
                        ++mb;
                    }
                }
                wcnt += total;
            }
        }

        #pragma unroll
        for (int j = 0; j < 4; ++j) { hP2[j] = hP1[j]; hP1[j] = hmC[j]; sP[j] = sC[j]; }
        r4 = r4n; u4 = u4n; er = ern; eu = eun; v = vn;
    }

    // ---- register sort of this wave's candidates (no barrier needed) ----
    const int m = (wcnt < WCAP) ? wcnt : WCAP;
    u64 a0, a1, a2, a3;
    if (m <= 128) {                      // fast path (~92% of waves)
        a0 = (lane      < m) ? myR[lane]      : 0ull;
        a1 = (lane + 64 < m) ? myR[lane + 64] : 0ull;
        sort128(a0, a1, lane);
        a2 = 0ull; a3 = 0ull;
    } else {
        a0 = (lane       < m) ? myR[lane]       : 0ull;
        a1 = (lane + 64  < m) ? myR[lane + 64]  : 0ull;
        a2 = (lane + 128 < m) ? myR[lane + 128] : 0ull;
        a3 = (lane + 192 < m) ? myR[lane + 192] : 0ull;
        sort256(a0, a1, a2, a3, lane);
    }

    u64* seg = top + ((size_t)b * NL1 + list) * KMAX;
    seg[lane]       = a0;
    seg[lane + 64]  = a1;
    seg[lane + 128] = a2;
    seg[lane + 192] = a3;
}

// ---------------------------------------------------------------------------
// K2: ONE WAVE per block. Register-merge 4 sorted lists -> 1.
// Used twice: 256 -> 64, then 64 -> 16.
// ---------------------------------------------------------------------------
__global__ __launch_bounds__(64)
void merge4_kernel(const u64* __restrict__ in, int nin,
                   u64* __restrict__ out_) {
    const int o    = blockIdx.x;
    const int b    = blockIdx.y;
    const int lane = threadIdx.x;

    const u64* L = in + ((size_t)b * nin + o * 4) * KMAX;

    u64 a0 = L[lane],            a1 = L[lane + 64],
        a2 = L[lane + 128],      a3 = L[lane + 192];
    {
        const u64 w0 = L[KMAX + lane],       w1 = L[KMAX + lane + 64],
                  w2 = L[KMAX + lane + 128], w3 = L[KMAX + lane + 192];
        merge256(a0, a1, a2, a3, w0, w1, w2, w3, lane);
    }
    u64 c0 = L[2 * KMAX + lane],        c1 = L[2 * KMAX + lane + 64],
        c2 = L[2 * KMAX + lane + 128],  c3 = L[2 * KMAX + lane + 192];
    {
        const u64 w0 = L[3 * KMAX + lane],       w1 = L[3 * KMAX + lane + 64],
                  w2 = L[3 * KMAX + lane + 128], w3 = L[3 * KMAX + lane + 192];
        merge256(c0, c1, c2, c3, w0, w1, w2, w3, lane);
    }
    merge256(a0, a1, a2, a3, c0, c1, c2, c3, lane);

    const int nout = nin / 4;
    u64* out = out_ + ((size_t)b * nout + o) * KMAX;
    out[lane]       = a0;
    out[lane + 64]  = a1;
    out[lane + 128] = a2;
    out[lane + 192] = a3;
}

// ---------------------------------------------------------------------------
// K3 (tail): 1 block/image x 512 threads. 16 sorted-desc 256-lists ->
// 4 rounds of pairwise top-256 merge (D[i] = max(A[i], B[255-i]) + 8-phase
// bitonic clean). Final list = exact sorted global top-256 -> ROI epilogue.
// ---------------------------------------------------------------------------
__global__ __launch_bounds__(TPB2)
void tail_kernel(const u64* __restrict__ mid,
                 const float* __restrict__ scale,
                 const float* __restrict__ unc,
                 const int* __restrict__ imh,
                 const int* __restrict__ imw,
                 float* __restrict__ rois,
                 float* __restrict__ scoresOut,
                 float* __restrict__ validOut) {
    const int b   = blockIdx.x;
    const int tid = threadIdx.x;

    __shared__ u64 bufA[NMID * KMAX];        // 32 KB
    __shared__ u64 bufB[(NMID / 2) * KMAX];  // 16 KB

    const u64* tb = mid + (size_t)b * NMID * KMAX;
    for (int i = tid; i < NMID * KMAX; i += TPB2) bufA[i] = tb[i];
    __syncthreads();

    u64* src = bufA;
    u64* dst = bufB;
    int nl = NMID;
    while (nl > 1) {
        const int half = nl >> 1;
        const int E = half * KMAX;
        for (int p = tid; p < E; p += TPB2) {
            const int h = p >> 8;
            const int i = p & (KMAX - 1);
            const u64 a = src[(2 * h) * KMAX + i];
            const u64 c = src[(2 * h + 1) * KMAX + (KMAX - 1 - i)];
            dst[p] = (a > c) ? a : c;
        }
        __syncthreads();
        for (int j = KMAX >> 1; j > 0; j >>= 1) {
            for (int p = tid; p < (E >> 1); p += TPB2) {
                const int i   = ((p & ~(j - 1)) << 1) | (p & (j - 1));
                const int ixj = i | j;
                const u64 a = dst[i];
                const u64 c = dst[ixj];
                if (a < c) { dst[i] = c; dst[ixj] = a; }
            }
            __syncthreads();
        }
        u64* t = src; src = dst; dst = t;
        nl = half;
    }

    if (tid < KMAX) {
        const u64 k = src[tid];
        const float value = __uint_as_float((unsigned)(k >> 32));
        const bool valid  = (k != 0ull) && (value > 0.0f);

        float r0 = 0.f, r1 = 0.f, r2 = 0.f, r3 = 0.f, r4 = 0.f, sv = 0.f, vv = 0.f;
        if (valid) {
            const unsigned idx = ~(unsigned)(k & 0xFFFFFFFFull);
            const int y = (int)(idx / IMW);
            const int x = (int)(idx % IMW);
            const float cx = ((float)x + 0.5f) * 4.0f;
            const float cy = ((float)y + 0.5f) * 4.0f;
            const float sg = scale[(size_t)b * IMH * IMW + idx];
            const float uu = unc[(size_t)b * IMH * IMW + idx];
            const float su = sigmoidf_(uu);
            float side = 32.0f + sigmoidf_(sg) * (512.0f - 32.0f);
            side = side * (1.0f + 0.25f * su);
            const float half2 = side * 0.5f;
            const float fw = (float)imw[0];
            const float fh = (float)imh[0];
            r0 = (float)b;
            r1 = fminf(fmaxf(cx - half2, 0.0f), fw - 1.0f);
            r2 = fminf(fmaxf(cy - half2, 0.0f), fh - 1.0f);
            r3 = fminf(fmaxf(cx + half2, 1.0f), fw);
            r4 = fminf(fmaxf(cy + half2, 1.0f), fh);
            sv = value;
            vv = 1.0f;
        }
        float* roiP = rois + ((size_t)b * KMAX + tid) * 5;
        roiP[0] = r0; roiP[1] = r1; roiP[2] = r2; roiP[3] = r3; roiP[4] = r4;
        scoresOut[b * KMAX + tid] = sv;
        validOut[b * KMAX + tid]  = vv;
    }
}

extern "C" void kernel_launch(void* const* d_in, const int* in_sizes, int n_in,
                              void* d_out, int out_size, void* d_ws, size_t ws_size,
                              hipStream_t stream) {
    const float* route = (const float*)d_in[0];
    const float* scale = (const float*)d_in[1];
    const float* unc   = (const float*)d_in[2];
    const int*   imh   = (const int*)d_in[3];
    const int*   imw   = (const int*)d_in[4];

    // ws layout: [top 256 lists = 16MB][mid1 64 = 4MB][mid2 16 = 1MB]
    u64* top  = (u64*)d_ws;
    u64* mid1 = top  + (size_t)BATCH * NL1 * KMAX;
    u64* mid2 = mid1 + (size_t)BATCH * NM1 * KMAX;

    float* rois      = (float*)d_out;                       // [B, 256, 5]
    float* scoresOut = rois + (size_t)BATCH * KMAX * 5;     // [B, 256]
    float* validOut  = scoresOut + (size_t)BATCH * KMAX;    // [B, 256]

    dim3 grid1(NBLKX, NYG, BATCH);         // 2 x 128 x 32 = 8192 wave-blocks
    score_nms_kernel<<<grid1, 64, 0, stream>>>(route, unc, top);

    dim3 grid2(NM1, BATCH);                // 64 x 32
    merge4_kernel<<<grid2, 64, 0, stream>>>(top, NL1, mid1);

    dim3 grid3(NMID, BATCH);               // 16 x 32
    merge4_kernel<<<grid3, 64, 0, stream>>>(mid1, NM1, mid2);

    tail_kernel<<<BATCH, TPB2, 0, stream>>>(mid2, scale, unc,
                                            imh, imw, rois, scoresOut, validOut);
}